// Round 1
// 706.881 us; speedup vs baseline: 1.2461x; 1.2461x over previous
//
#include <hip/hip_runtime.h>
#include <cstdint>

#define DEV __device__ __forceinline__

constexpr int Bz = 8, Tz = 4096, Cz = 1024;
constexpr int Mz = Bz * Tz;           // 32768 rows
constexpr int Sz = 32, Lz = 128;      // scan: 32 chunks x 128 steps = T

using bf16x8  = __attribute__((ext_vector_type(8))) __bf16;
using floatx4 = __attribute__((ext_vector_type(4))) float;

DEV float bf2f(unsigned short u) { return __uint_as_float(((uint32_t)u) << 16); }
DEV unsigned short f2bf(float f) {            // round-to-nearest-even
    uint32_t u = __float_as_uint(f);
    u += 0x7fffu + ((u >> 16) & 1u);
    return (unsigned short)(u >> 16);
}
DEV unsigned short f2h(float f) {
    _Float16 h = (_Float16)f;
    unsigned short u;
    __builtin_memcpy(&u, &h, 2);
    return u;
}
DEV float h2f(unsigned short u) {
    _Float16 h;
    __builtin_memcpy(&h, &u, 2);
    return (float)h;
}

DEV void gl2lds16(const unsigned short* g, unsigned short* l) {
    __builtin_amdgcn_global_load_lds(
        (const __attribute__((address_space(1))) void*)g,
        (__attribute__((address_space(3))) void*)l, 16, 0, 0);
}

DEV void barmem() {
    asm volatile("" ::: "memory");
    __builtin_amdgcn_s_barrier();
    asm volatile("" ::: "memory");
}

// swizzled fragment read: LDS granule (row, cg) holds global granule cg^(row&7)
DEV bf16x8 ldfrag(const unsigned short* slot, int row, int kg) {
    return *(const bf16x8*)&slot[row * 64 + ((kg ^ (row & 7)) << 3)];
}

// ---------------- weight fp32 -> bf16 (all 4 weights, one dispatch) ----------------
__global__ __launch_bounds__(256) void f2b_k(const float* __restrict__ w0,
                                             const float* __restrict__ w1,
                                             const float* __restrict__ w2,
                                             const float* __restrict__ w3,
                                             unsigned short* __restrict__ dst) {
    int which = blockIdx.y;
    const float* src = which == 0 ? w0 : which == 1 ? w1 : which == 2 ? w2 : w3;
    int i = blockIdx.x * 256 + threadIdx.x;          // float4 idx within one weight
    float4 v = ((const float4*)src)[i];
    ushort4 o;
    o.x = f2bf(v.x); o.y = f2bf(v.y); o.z = f2bf(v.z); o.w = f2bf(v.w);
    ((ushort4*)(dst + (size_t)which * Cz * Cz))[i] = o;
}

// ---------------- time-mix: xk/xv/xr (bf16) ----------------
DEV ushort4 mix4(float4 m, float4 xc, float4 xp) {
    ushort4 o;
    o.x = f2bf(fmaf(m.x, xc.x - xp.x, xp.x));
    o.y = f2bf(fmaf(m.y, xc.y - xp.y, xp.y));
    o.z = f2bf(fmaf(m.z, xc.z - xp.z, xp.z));
    o.w = f2bf(fmaf(m.w, xc.w - xp.w, xp.w));
    return o;
}

__global__ __launch_bounds__(256) void mix_k(const float* __restrict__ x,
    const float* __restrict__ mk, const float* __restrict__ mv, const float* __restrict__ mr,
    unsigned short* __restrict__ xk, unsigned short* __restrict__ xv,
    unsigned short* __restrict__ xr) {
    int gid = blockIdx.x * 256 + threadIdx.x;       // float4 group; total Mz*Cz/4
    int m   = gid >> 8;                             // row = b*T + t   (Cz/4 = 256)
    int c4  = gid & 255;
    float4 xc = ((const float4*)x)[gid];
    float4 xp = make_float4(0.f, 0.f, 0.f, 0.f);
    if ((m & (Tz - 1)) != 0) xp = ((const float4*)x)[gid - 256];   // x[b, t-1]
    ((ushort4*)xk)[gid] = mix4(((const float4*)mk)[c4], xc, xp);
    ((ushort4*)xv)[gid] = mix4(((const float4*)mv)[c4], xc, xp);
    ((ushort4*)xr)[gid] = mix4(((const float4*)mr)[c4], xc, xp);
}

// ---------------- bf16 NT GEMM, 256x256 tile, BK=64, 8-phase counted-vmcnt ----------
// C[m,n] = sum_k A[m,k] * Bw[n,k];  M=32768, N=K=1024
// 1-D grid (512 wg per gemm), 512 threads (8 waves, 2Mx4N). modes packed 4b each:
//   0: fp32 store; 1: bf16; 2: sigmoid->bf16; 3: f16
// LDS ring: 8 half-tile slots of 16 KB ([128][64] bf16, granule-XOR swizzled).
//   half-tile h: tile=h>>2, kind=h&3 (0/1 = A rows +0/+128, 2/3 = B rows +0/+128),
//   slot = h&7. Stage schedule leads consumption by 6 phases; boundary vmcnt(4).
__global__ __launch_bounds__(512, 2) void gemm256(
        const unsigned short* __restrict__ A0, const unsigned short* __restrict__ A1,
        const unsigned short* __restrict__ A2,
        const unsigned short* __restrict__ Bw0, const unsigned short* __restrict__ Bw1,
        const unsigned short* __restrict__ Bw2,
        void* __restrict__ O0, void* __restrict__ O1, void* __restrict__ O2,
        int modes) {
    constexpr int Kd = 1024, Nd = 1024, NT = 16;       // NT = K / 64
    __shared__ __align__(16) unsigned short lds[8 * 8192];   // 128 KiB

    // bijective XCD swizzle (gridDim.x % 8 == 0)
    const int cpx = gridDim.x >> 3;
    const int L   = (blockIdx.x & 7) * cpx + (blockIdx.x >> 3);
    const int z   = L >> 9;                 // 512 wg per gemm
    const int rr  = L & 511;
    const int m0  = (rr >> 2) << 8;         // 128 m-blocks
    const int n0  = (rr & 3) << 8;          // 4 n-blocks

    const unsigned short* A  = z == 0 ? A0  : z == 1 ? A1  : A2;
    const unsigned short* Bw = z == 0 ? Bw0 : z == 1 ? Bw1 : Bw2;
    void* Cout = z == 0 ? O0 : z == 1 ? O1 : O2;
    const int mode = (modes >> (z * 4)) & 15;

    const int tid  = threadIdx.x;
    const int lane = tid & 63;
    const int wave = tid >> 6;              // 0..7
    const int wr   = wave >> 2;             // row half of the 256-tile
    const int wc   = wave & 3;              // col quarter (64 wide)
    const int l15  = lane & 15, kseg = lane >> 4;
    const int brow = (wc & 1) * 64;         // B row base within its half slot

    // staging constants: thread covers granules g0 and g0+64 of each half-tile
    const int g0   = wave * 128 + lane;
    const int row0 = g0 >> 3;
    const int scg0 = (g0 & 7) ^ (row0 & 7); // pre-swizzled global granule
    const size_t soff0 = (size_t)row0 * Kd + scg0 * 8;
    const int sd0  = g0 * 8;                // linear LDS dest (ushort)

    auto STAGE = [&](int hh) {
        if (hh >= 4 * NT) return;
        const int kind = hh & 3;
        const unsigned short* mat = (kind & 2) ? Bw : A;
        const int rbase = ((kind & 2) ? n0 : m0) + ((kind & 1) << 7);
        const unsigned short* sb = mat + (size_t)rbase * Kd + ((hh >> 2) << 6);
        unsigned short* db = &lds[(hh & 7) * 8192];
        gl2lds16(sb + soff0,            db + sd0);
        gl2lds16(sb + soff0 + 8 * Kd,   db + sd0 + 512);   // row+8, same swizzle
    };

    floatx4 acc[8][4];
#pragma unroll
    for (int mi = 0; mi < 8; mi++)
#pragma unroll
        for (int ni = 0; ni < 4; ni++) acc[mi][ni] = (floatx4){0.f, 0.f, 0.f, 0.f};

    auto QUAD = [&](const bf16x8 (&af)[4], const bf16x8 (&bfv)[4], int mo) {
#pragma unroll
        for (int i = 0; i < 4; i++)
#pragma unroll
            for (int n = 0; n < 4; n++)
                acc[mo + i][n] = __builtin_amdgcn_mfma_f32_16x16x32_bf16(
                    af[i], bfv[n], acc[mo + i][n], 0, 0, 0);
    };

    // prologue: tile0 (h0-3) + tile1 A halves (h4,5); need h0-3 done -> vmcnt(4)
#pragma unroll
    for (int hh = 0; hh < 6; hh++) STAGE(hh);
    asm volatile("s_waitcnt vmcnt(4)" ::: "memory");
    barmem();

#pragma unroll 2
    for (int t = 0; t < NT; t++) {
        const unsigned short* sA = &lds[(((t & 1) << 2) + wr) * 8192];
        const unsigned short* sB = &lds[(((t & 1) << 2) + 2 + (wc >> 1)) * 8192];
        const int bh = 4 * t + 6;
        bf16x8 a00[4], a01[4], a10[4], a11[4], b0[4], b1[4];

        // ---- phase 0: read A(mh0,ks0+ks1) + B(ks0) = 12 reads; MFMA (mh0,ks0)
#pragma unroll
        for (int i = 0; i < 4; i++) {
            int ra = i * 16 + l15;
            a00[i] = ldfrag(sA, ra, kseg);
            a01[i] = ldfrag(sA, ra, 4 + kseg);
            b0[i]  = ldfrag(sB, brow + i * 16 + l15, kseg);
        }
        STAGE(bh + 0);
        barmem();
        asm volatile("s_waitcnt lgkmcnt(4)" ::: "memory");
        __builtin_amdgcn_s_setprio(1);
        QUAD(a00, b0, 0);
        __builtin_amdgcn_s_setprio(0);
        barmem();

        // ---- phase 1: read A(mh1,ks0+ks1) = 8 reads; MFMA (mh1,ks0)
        // lgkmcnt(0) here drains ALL A-slot reads before the A slots are
        // overwritten by STAGE(bh+2/3) (R->W ledger).
#pragma unroll
        for (int i = 0; i < 4; i++) {
            int ra = 64 + i * 16 + l15;
            a10[i] = ldfrag(sA, ra, kseg);
            a11[i] = ldfrag(sA, ra, 4 + kseg);
        }
        STAGE(bh + 1);
        barmem();
        asm volatile("s_waitcnt lgkmcnt(0)" ::: "memory");
        __builtin_amdgcn_s_setprio(1);
        QUAD(a10, b0, 4);
        __builtin_amdgcn_s_setprio(0);
        barmem();

        // ---- phase 2: read B(ks1) = 4 reads; MFMA (mh0,ks1)
#pragma unroll
        for (int i = 0; i < 4; i++)
            b1[i] = ldfrag(sB, brow + i * 16 + l15, 4 + kseg);
        STAGE(bh + 2);
        barmem();
        asm volatile("s_waitcnt lgkmcnt(0)" ::: "memory");
        __builtin_amdgcn_s_setprio(1);
        QUAD(a01, b1, 0);
        __builtin_amdgcn_s_setprio(0);
        barmem();

        // ---- phase 3: MFMA (mh1,ks1); counted vmcnt at tile boundary
        STAGE(bh + 3);
        barmem();
        __builtin_amdgcn_s_setprio(1);
        QUAD(a11, b1, 4);
        __builtin_amdgcn_s_setprio(0);
        if (t < NT - 2) asm volatile("s_waitcnt vmcnt(4)" ::: "memory");
        else            asm volatile("s_waitcnt vmcnt(0)" ::: "memory");
        barmem();
    }

    // epilogue: D col = lane&15, row = (lane>>4)*4 + reg   [m89 verified]
    const int cr = kseg * 4;
#pragma unroll
    for (int mi = 0; mi < 8; mi++) {
#pragma unroll
        for (int ni = 0; ni < 4; ni++) {
            size_t row = (size_t)(m0 + wr * 128 + mi * 16 + cr);
            size_t col = (size_t)(n0 + wc * 64 + ni * 16 + l15);
#pragma unroll
            for (int rg = 0; rg < 4; rg++) {
                float v = acc[mi][ni][rg];
                size_t idx = (row + rg) * Nd + col;
                if (mode == 0) {
                    ((float*)Cout)[idx] = v;
                } else if (mode == 1) {
                    ((unsigned short*)Cout)[idx] = f2bf(v);
                } else if (mode == 2) {
                    float sg = 1.0f / (1.0f + __expf(-v));
                    ((unsigned short*)Cout)[idx] = f2bf(sg);
                } else {
                    ((unsigned short*)Cout)[idx] = f2h(v);
                }
            }
        }
    }
}

// ---------------- WKV scan, 3-pass chunked linear recurrence ----------------
__global__ __launch_bounds__(256) void wkv_pass1(const unsigned short* __restrict__ kh,
    const unsigned short* __restrict__ vb, const float* __restrict__ td,
    float2* __restrict__ SA, float2* __restrict__ SB) {
    int tid = blockIdx.x * 256 + threadIdx.x;   // B*S*C/2 threads
    int c2  = tid & 511;
    int bs  = tid >> 9;                         // b*S + s
    int b   = bs >> 5, s = bs & (Sz - 1);
    int c   = c2 * 2;
    float lam0 = __expf(-__expf(td[c]));
    float lam1 = __expf(-__expf(td[c + 1]));
    size_t base = (((size_t)(b * Tz + s * Lz)) * Cz + c) >> 1;   // ushort2 index
    float pa0 = 0.f, pb0 = 0.f, pa1 = 0.f, pb1 = 0.f;
#pragma unroll 4
    for (int i = 0; i < Lz; i++) {
        size_t idx = base + (size_t)i * (Cz / 2);
        ushort2 kk = ((const ushort2*)kh)[idx];
        ushort2 vv = ((const ushort2*)vb)[idx];
        float e0 = __expf(h2f(kk.x)), e1 = __expf(h2f(kk.y));
        pa0 = fmaf(pa0, lam0, e0 * bf2f(vv.x));
        pb0 = fmaf(pb0, lam0, e0);
        pa1 = fmaf(pa1, lam1, e1 * bf2f(vv.y));
        pb1 = fmaf(pb1, lam1, e1);
    }
    SA[tid] = make_float2(pa0, pa1);   // layout (b*S+s)*512 + c2
    SB[tid] = make_float2(pb0, pb1);
}

__global__ __launch_bounds__(256) void wkv_pass2(const float* __restrict__ td,
                                                 float2* __restrict__ SA,
                                                 float2* __restrict__ SB) {
    int tid = blockIdx.x * 256 + threadIdx.x;   // B*C/2 threads
    int c2  = tid & 511;
    int b   = tid >> 9;
    int c   = c2 * 2;
    float lamL0 = __expf(-__expf(td[c]) * (float)Lz);
    float lamL1 = __expf(-__expf(td[c + 1]) * (float)Lz);
    float A0 = 0.f, B0 = 0.f, A1 = 0.f, B1 = 0.f;
    for (int s = 0; s < Sz; s++) {
        size_t idx = ((size_t)(b * Sz + s)) * 512 + c2;
        float2 ta = SA[idx], tb = SB[idx];
        SA[idx] = make_float2(A0, A1);          // exclusive prefix = chunk-start state
        SB[idx] = make_float2(B0, B1);
        A0 = fmaf(A0, lamL0, ta.x);  B0 = fmaf(B0, lamL0, tb.x);
        A1 = fmaf(A1, lamL1, ta.y);  B1 = fmaf(B1, lamL1, tb.y);
    }
}

__global__ __launch_bounds__(256) void wkv_pass3(const unsigned short* __restrict__ kh,
    const unsigned short* __restrict__ vb, const unsigned short* __restrict__ rb,
    const float* __restrict__ td, const float* __restrict__ tf,
    const float2* __restrict__ SA, const float2* __restrict__ SB,
    unsigned short* __restrict__ ry) {
    int tid = blockIdx.x * 256 + threadIdx.x;
    int c2  = tid & 511;
    int bs  = tid >> 9;
    int b   = bs >> 5, s = bs & (Sz - 1);
    int c   = c2 * 2;
    float lam0 = __expf(-__expf(td[c]));
    float lam1 = __expf(-__expf(td[c + 1]));
    float eu0  = __expf(tf[c]);
    float eu1  = __expf(tf[c + 1]);
    float2 fa = SA[tid], fb = SB[tid];
    float A0 = fa.x, A1 = fa.y, B0 = fb.x, B1 = fb.y;
    size_t base = (((size_t)(b * Tz + s * Lz)) * Cz + c) >> 1;
#pragma unroll 2
    for (int i = 0; i < Lz; i++) {
        size_t idx = base + (size_t)i * (Cz / 2);
        ushort2 kk = ((const ushort2*)kh)[idx];
        ushort2 vv = ((const ushort2*)vb)[idx];
        ushort2 rr = ((const ushort2*)rb)[idx];
        float e0 = __expf(h2f(kk.x)), e1 = __expf(h2f(kk.y));
        float ev0 = e0 * bf2f(vv.x), ev1 = e1 * bf2f(vv.y);
        float y0 = fmaf(A0, eu0, ev0) * __builtin_amdgcn_rcpf(fmaf(B0, eu0, e0));
        float y1 = fmaf(A1, eu1, ev1) * __builtin_amdgcn_rcpf(fmaf(B1, eu1, e1));
        ushort2 o;
        o.x = f2bf(bf2f(rr.x) * y0);
        o.y = f2bf(bf2f(rr.y) * y1);
        ((ushort2*)ry)[idx] = o;
        A0 = fmaf(A0, lam0, ev0);  B0 = fmaf(B0, lam0, e0);
        A1 = fmaf(A1, lam1, ev1);  B1 = fmaf(B1, lam1, e1);
    }
}

// ---------------- launcher ----------------
extern "C" void kernel_launch(void* const* d_in, const int* in_sizes, int n_in,
                              void* d_out, int out_size, void* d_ws, size_t ws_size,
                              hipStream_t stream) {
    const float* x  = (const float*)d_in[0];
    const float* td = (const float*)d_in[1];
    const float* tf = (const float*)d_in[2];
    const float* mk = (const float*)d_in[3];
    const float* mv = (const float*)d_in[4];
    const float* mr = (const float*)d_in[5];
    const float* Wk = (const float*)d_in[6];
    const float* Wv = (const float*)d_in[7];
    const float* Wr = (const float*)d_in[8];
    const float* Wo = (const float*)d_in[9];

    constexpr size_t SZ_BF = (size_t)Mz * Cz * 2;       // 64 MB
    constexpr size_t SZ_W  = (size_t)Cz * Cz * 2;       // 2 MB
    constexpr size_t SZ_S  = (size_t)Bz * Sz * Cz * 4;  // 1 MB

    char* ws = (char*)d_ws;
    unsigned short* xk  = (unsigned short*)(ws);
    unsigned short* xv  = (unsigned short*)(ws + SZ_BF);
    unsigned short* xr  = (unsigned short*)(ws + 2 * SZ_BF);
    unsigned short* kf  = (unsigned short*)(ws + 3 * SZ_BF);   // f16
    unsigned short* vb  = (unsigned short*)(ws + 4 * SZ_BF);   // bf16
    unsigned short* rb  = (unsigned short*)(ws + 5 * SZ_BF);   // bf16
    unsigned short* wts = (unsigned short*)(ws + 6 * SZ_BF);   // wk|wv|wr|wo
    float2*         SA  = (float2*)        (ws + 6 * SZ_BF + 4 * SZ_W);
    float2*         SB  = (float2*)        (ws + 6 * SZ_BF + 4 * SZ_W + SZ_S);
    unsigned short* wkb = wts;
    unsigned short* wvb = wts + (size_t)Cz * Cz;
    unsigned short* wrb = wts + (size_t)2 * Cz * Cz;
    unsigned short* wob = wts + (size_t)3 * Cz * Cz;
    unsigned short* ry  = xk;   // xk dead after k-GEMM; reuse for r*y

    f2b_k<<<dim3(Cz * Cz / 4 / 256, 4), dim3(256), 0, stream>>>(Wk, Wv, Wr, Wo, wts);

    mix_k<<<dim3(Mz * Cz / 4 / 256), dim3(256), 0, stream>>>(x, mk, mv, mr, xk, xv, xr);

    // fused k/v/r GEMMs: z=0 k->f16, z=1 v->bf16, z=2 r->sigmoid bf16
    gemm256<<<dim3(512 * 3), dim3(512), 0, stream>>>(
        xk, xv, xr, wkb, wvb, wrb, (void*)kf, (void*)vb, (void*)rb,
        (3) | (1 << 4) | (2 << 8));

    wkv_pass1<<<dim3(Bz * Sz * Cz / 2 / 256), dim3(256), 0, stream>>>(kf, vb, td, SA, SB);
    wkv_pass2<<<dim3(Bz * Cz / 2 / 256), dim3(256), 0, stream>>>(td, SA, SB);
    wkv_pass3<<<dim3(Bz * Sz * Cz / 2 / 256), dim3(256), 0, stream>>>(kf, vb, rb, td, tf,
                                                                      SA, SB, ry);

    // out = (r*y) @ Wo^T, fp32
    gemm256<<<dim3(512), dim3(512), 0, stream>>>(
        ry, ry, ry, wob, wob, wob, d_out, d_out, d_out, 0);
}